// Round 5
// baseline (1508.953 us; speedup 1.0000x reference)
//
#include <hip/hip_runtime.h>
#include <math.h>

// KNNGraph(2) on N=16384 points, D=64, fp32.
// adjacency = I + one-hot(nearest other neighbor) per row.
// argmin_j (sq[j] - 2*dot(x_i,x_j)), j != i  (sq[i] term is row-constant).
//
// R2: fixed catastrophic scratch spill (61.5 GB HBM -> 12 MB, 25.5ms -> 717us).
// R3: folded output zeroing into knn_kernel (hides 1.07-GB stream under compute).
// R4: counters showed knn is write-DRAIN-bound: __syncthreads emits
//     s_waitcnt vmcnt(0) before s_barrier, force-draining the 64-KB/CU store
//     burst every tile (28.1k cyc/tile at the measured 1.43 TB/s = the wall).
//     In-loop barriers only need to order LDS, so use raw
//     "s_waitcnt lgkmcnt(0); s_barrier" -> stores become fire-and-forget and
//     stream at HBM write rate under the LDS-bound GEMM.

#define NPTS 16384
#define DIM 64
#define BM 128          // rows per block
#define BN 64           // cols per j-tile
#define TM 8            // rows per thread
#define TN 4            // cols per thread
#define NTHR 256        // 16x16 thread layout
#define JSPLIT 4        // split j-range for occupancy (2 blocks/CU)
#define JRANGE (NPTS / JSPLIT)   // 4096
#define NJT (JRANGE / BN)        // 64 tiles
#define LS 68           // LDS row stride in floats: 272 B = 16B aligned, bank-spread

// LDS-only barrier: waits ds ops (lgkmcnt) but NOT outstanding global stores
// (vmcnt). Safe here because nothing in this kernel reads `out`, and the
// "memory" clobber pins all memory ops on their side of the barrier.
#define LDS_BARRIER() asm volatile("s_waitcnt lgkmcnt(0)\n\ts_barrier" ::: "memory")

__global__ void sq_kernel(const float* __restrict__ X, float* __restrict__ sqout) {
  int i = blockIdx.x * NTHR + threadIdx.x;
  const float4* x4 = (const float4*)(X + (size_t)i * DIM);
  float s = 0.f;
#pragma unroll
  for (int k = 0; k < DIM / 4; ++k) {
    float4 v = x4[k];
    s = fmaf(v.x, v.x, s); s = fmaf(v.y, v.y, s);
    s = fmaf(v.z, v.z, s); s = fmaf(v.w, v.w, s);
  }
  sqout[i] = s;
}

__global__ __launch_bounds__(NTHR, 2) void knn_kernel(
    const float* __restrict__ X, const float* __restrict__ sqn,
    float* __restrict__ out, float* __restrict__ cand_val, int* __restrict__ cand_idx) {
  __shared__ float As[BM * LS];   // 34816 B
  __shared__ float Bs[BN * LS];   // 17408 B
  __shared__ float sqt[BN];

  const int tid = threadIdx.x;
  const int tx = tid & 15;
  const int ty = tid >> 4;
  const int ib = blockIdx.x >> 2;   // / JSPLIT
  const int jh = blockIdx.x & 3;    // % JSPLIT
  const int i0 = ib * BM;
  const int j0base = jh * JRANGE;

  // Stage A tile (BM x DIM) once: coalesced float4 loads.
  {
    const float4* src = (const float4*)(X + (size_t)i0 * DIM);
#pragma unroll
    for (int p = 0; p < (BM * DIM / 4) / NTHR; ++p) {
      int f4 = tid + NTHR * p;
      int r = f4 >> 4, c = f4 & 15;   // 16 float4 per row
      float4 v = src[f4];
      *(float4*)(&As[r * LS + c * 4]) = v;
    }
  }

  float bestv[TM];
  int besti[TM];
#pragma unroll
  for (int mk = 0; mk < TM; ++mk) { bestv[mk] = INFINITY; besti[mk] = 0x7fffffff; }

#pragma unroll 1   // keep the tile loop a real loop: bound register live ranges
  for (int jt = 0; jt < NJT; ++jt) {
    const int j0 = j0base + jt * BN;
    LDS_BARRIER();   // protect Bs from previous iteration's readers (LDS-only)
    // Stage B tile (BN x DIM)
    {
      const float4* src = (const float4*)(X + (size_t)j0 * DIM);
#pragma unroll
      for (int p = 0; p < (BN * DIM / 4) / NTHR; ++p) {
        int f4 = tid + NTHR * p;
        int r = f4 >> 4, c = f4 & 15;
        float4 v = src[f4];
        *(float4*)(&Bs[r * LS + c * 4]) = v;
      }
      if (tid < BN) sqt[tid] = sqn[j0 + tid];
    }
    LDS_BARRIER();   // Bs ready (LDS-only; zero-stores keep streaming)

    // Zero this block's output stripe (BM x BN) for this tile. Fire-and-forget:
    // no vmcnt(0) anywhere in the loop, so these drain continuously at HBM
    // write rate underneath the GEMM.
    {
#pragma unroll
      for (int p = 0; p < (BM * BN / 4) / NTHR; ++p) {
        int f4 = tid + NTHR * p;
        int r = f4 >> 4;      // 16 float4 per row
        int c = f4 & 15;
        *(float4*)(out + (size_t)(i0 + r) * NPTS + j0 + c * 4) =
            make_float4(0.f, 0.f, 0.f, 0.f);
      }
    }

    float acc[TM][TN];
#pragma unroll
    for (int mk = 0; mk < TM; ++mk)
#pragma unroll
      for (int nk = 0; nk < TN; ++nk) acc[mk][nk] = 0.f;

    // Register-lean GEMM: keep only b[4] (16 VGPRs) resident per d0-step,
    // stream A-fragments one float4 at a time. Live set ~85 VGPRs -> no
    // scratch even under a conservative allocator.
#pragma unroll 2
    for (int d0 = 0; d0 < DIM; d0 += 4) {
      float4 b[TN];
#pragma unroll
      for (int nk = 0; nk < TN; ++nk)
        b[nk] = *(const float4*)(&Bs[(tx + 16 * nk) * LS + d0]);
#pragma unroll
      for (int mk = 0; mk < TM; ++mk) {
        float4 av = *(const float4*)(&As[(ty + 16 * mk) * LS + d0]);
#pragma unroll
        for (int nk = 0; nk < TN; ++nk) {
          acc[mk][nk] = fmaf(av.x, b[nk].x, acc[mk][nk]);
          acc[mk][nk] = fmaf(av.y, b[nk].y, acc[mk][nk]);
          acc[mk][nk] = fmaf(av.z, b[nk].z, acc[mk][nk]);
          acc[mk][nk] = fmaf(av.w, b[nk].w, acc[mk][nk]);
        }
      }
    }

    // Update running argmin (j visited in increasing order per thread).
#pragma unroll
    for (int nk = 0; nk < TN; ++nk) {
      const int j = j0 + tx + 16 * nk;
      const float sj = sqt[tx + 16 * nk];
#pragma unroll
      for (int mk = 0; mk < TM; ++mk) {
        const int irow = i0 + ty + 16 * mk;
        float v = fmaf(-2.f, acc[mk][nk], sj);
        if (j != irow && (v < bestv[mk] || (v == bestv[mk] && j < besti[mk]))) {
          bestv[mk] = v;
          besti[mk] = j;
        }
      }
    }
  }

  // Cross-thread reduction: row m is owned by the 16 tx-threads of its ty.
  // Full __syncthreads here (outside the hot loop; one drain is fine).
  __syncthreads();
  float* rv = As;        // [BM][16] floats (8 KB, fits in As)
  int* ri = (int*)Bs;    // [BM][16] ints  (8 KB, fits in Bs)
#pragma unroll
  for (int mk = 0; mk < TM; ++mk) {
    int m = ty + 16 * mk;
    rv[m * 16 + tx] = bestv[mk];
    ri[m * 16 + tx] = besti[mk];
  }
  __syncthreads();
  if (tid < BM) {
    float bv = INFINITY;
    int bi = 0x7fffffff;
#pragma unroll
    for (int t = 0; t < 16; ++t) {
      float v = rv[tid * 16 + t];
      int ix = ri[tid * 16 + t];
      if (v < bv || (v == bv && ix < bi)) { bv = v; bi = ix; }
    }
    cand_val[(size_t)(i0 + tid) * JSPLIT + jh] = bv;
    cand_idx[(size_t)(i0 + tid) * JSPLIT + jh] = bi;
  }
}

__global__ void merge_kernel(const float* __restrict__ cand_val,
                             const int* __restrict__ cand_idx,
                             float* __restrict__ out) {
  int i = blockIdx.x * NTHR + threadIdx.x;
  float bv = INFINITY;
  int bi = 0x7fffffff;
#pragma unroll
  for (int s = 0; s < JSPLIT; ++s) {
    float v = cand_val[(size_t)i * JSPLIT + s];
    int ix = cand_idx[(size_t)i * JSPLIT + s];
    if (v < bv || (v == bv && ix < bi)) { bv = v; bi = ix; }
  }
  out[(size_t)i * NPTS + i] = 1.0f;   // self is always nearest (dist ~ 0)
  out[(size_t)i * NPTS + bi] = 1.0f;  // nearest other neighbor
}

extern "C" void kernel_launch(void* const* d_in, const int* in_sizes, int n_in,
                              void* d_out, int out_size, void* d_ws, size_t ws_size,
                              hipStream_t stream) {
  const float* X = (const float*)d_in[0];
  float* out = (float*)d_out;

  // Workspace layout: sq[N] | cand_val[N*JSPLIT] | cand_idx[N*JSPLIT]  (~576 KB)
  float* sq = (float*)d_ws;
  float* cand_val = sq + NPTS;
  int* cand_idx = (int*)(cand_val + (size_t)NPTS * JSPLIT);

  sq_kernel<<<NPTS / NTHR, NTHR, 0, stream>>>(X, sq);
  knn_kernel<<<(NPTS / BM) * JSPLIT, NTHR, 0, stream>>>(X, sq, out, cand_val, cand_idx);
  merge_kernel<<<NPTS / NTHR, NTHR, 0, stream>>>(cand_val, cand_idx, out);
}

// Round 6
// 1444.364 us; speedup vs baseline: 1.0447x; 1.0447x over previous
//
#include <hip/hip_runtime.h>
#include <math.h>

// KNNGraph(2) on N=16384 points, D=64, fp32.
// adjacency = I + one-hot(nearest other neighbor) per row.
// argmin_j (sq[j] - 2*dot(x_i,x_j)), j != i  (sq[i] term is row-constant).
//
// R2: fixed catastrophic scratch spill (61.5 GB HBM -> 12 MB, 25.5ms -> 717us).
// R3: folded output zeroing into knn_kernel (hides 1.07-GB stream under compute).
// R4/R5: LDS-only in-loop barriers (s_waitcnt lgkmcnt(0); s_barrier) so zero
//     stores are fire-and-forget. Neutral vs R3 -> writes were never the limit.
// R6: counters say LDS-throughput-bound (1536 ds_read_b128/CU/tile = 18.4k cyc
//     vs 8.2k FMA). Widen register tile to TM=8 x TN=8 (BN=128): 1.0 B/MAC
//     instead of 1.5, and half the tile iterations -> half the barrier/argmin
//     overhead. VGPR ~180 still fits 2 blocks/CU (cap 256); LDS 70.1 KB.

#define NPTS 16384
#define DIM 64
#define BM 128          // rows per block
#define BN 128          // cols per j-tile
#define TM 8            // rows per thread
#define TN 8            // cols per thread
#define NTHR 256        // 16x16 thread layout
#define JSPLIT 4        // split j-range for occupancy (2 blocks/CU)
#define JRANGE (NPTS / JSPLIT)   // 4096
#define NJT (JRANGE / BN)        // 32 tiles
#define LS 68           // LDS row stride in floats: 272 B = 16B aligned, bank-spread

// LDS-only barrier: waits ds ops (lgkmcnt) but NOT outstanding global stores
// (vmcnt). Safe: nothing in this kernel reads `out`; "memory" clobber pins
// memory ops on their side of the barrier.
#define LDS_BARRIER() asm volatile("s_waitcnt lgkmcnt(0)\n\ts_barrier" ::: "memory")

__global__ void sq_kernel(const float* __restrict__ X, float* __restrict__ sqout) {
  int i = blockIdx.x * NTHR + threadIdx.x;
  const float4* x4 = (const float4*)(X + (size_t)i * DIM);
  float s = 0.f;
#pragma unroll
  for (int k = 0; k < DIM / 4; ++k) {
    float4 v = x4[k];
    s = fmaf(v.x, v.x, s); s = fmaf(v.y, v.y, s);
    s = fmaf(v.z, v.z, s); s = fmaf(v.w, v.w, s);
  }
  sqout[i] = s;
}

__global__ __launch_bounds__(NTHR, 2) void knn_kernel(
    const float* __restrict__ X, const float* __restrict__ sqn,
    float* __restrict__ out, float* __restrict__ cand_val, int* __restrict__ cand_idx) {
  __shared__ float As[BM * LS];   // 34816 B
  __shared__ float Bs[BN * LS];   // 34816 B
  __shared__ float sqt[BN];       // 512 B      -> 70144 B total, 2 blocks/CU

  const int tid = threadIdx.x;
  const int tx = tid & 15;
  const int ty = tid >> 4;
  const int ib = blockIdx.x >> 2;   // / JSPLIT
  const int jh = blockIdx.x & 3;    // % JSPLIT
  const int i0 = ib * BM;
  const int j0base = jh * JRANGE;

  // Stage A tile (BM x DIM) once: coalesced float4 loads.
  {
    const float4* src = (const float4*)(X + (size_t)i0 * DIM);
#pragma unroll
    for (int p = 0; p < (BM * DIM / 4) / NTHR; ++p) {
      int f4 = tid + NTHR * p;
      int r = f4 >> 4, c = f4 & 15;   // 16 float4 per row
      float4 v = src[f4];
      *(float4*)(&As[r * LS + c * 4]) = v;
    }
  }

  float bestv[TM];
  int besti[TM];
#pragma unroll
  for (int mk = 0; mk < TM; ++mk) { bestv[mk] = INFINITY; besti[mk] = 0x7fffffff; }

#pragma unroll 1   // keep the tile loop a real loop: bound register live ranges
  for (int jt = 0; jt < NJT; ++jt) {
    const int j0 = j0base + jt * BN;
    LDS_BARRIER();   // protect Bs from previous iteration's readers (LDS-only)
    // Stage B tile (BN x DIM)
    {
      const float4* src = (const float4*)(X + (size_t)j0 * DIM);
#pragma unroll
      for (int p = 0; p < (BN * DIM / 4) / NTHR; ++p) {
        int f4 = tid + NTHR * p;
        int r = f4 >> 4, c = f4 & 15;
        float4 v = src[f4];
        *(float4*)(&Bs[r * LS + c * 4]) = v;
      }
      if (tid < BN) sqt[tid] = sqn[j0 + tid];
    }
    LDS_BARRIER();   // Bs ready (LDS-only; zero-stores keep streaming)

    // Zero this block's output stripe (BM x BN). Fire-and-forget: no vmcnt(0)
    // in the loop, drains continuously under the GEMM.
    {
#pragma unroll
      for (int p = 0; p < (BM * BN / 4) / NTHR; ++p) {
        int f4 = tid + NTHR * p;
        int r = f4 >> 5;      // 32 float4 per row
        int c = f4 & 31;
        *(float4*)(out + (size_t)(i0 + r) * NPTS + j0 + c * 4) =
            make_float4(0.f, 0.f, 0.f, 0.f);
      }
    }

    float acc[TM][TN];
#pragma unroll
    for (int mk = 0; mk < TM; ++mk)
#pragma unroll
      for (int nk = 0; nk < TN; ++nk) acc[mk][nk] = 0.f;

    // 8x8 register tile: 16 ds_read_b128 feed 256 FMAs per d0-step
    // (1.0 B/MAC). Only b[8] + one streamed av live beyond acc.
#pragma unroll 2
    for (int d0 = 0; d0 < DIM; d0 += 4) {
      float4 b[TN];
#pragma unroll
      for (int nk = 0; nk < TN; ++nk)
        b[nk] = *(const float4*)(&Bs[(tx + 16 * nk) * LS + d0]);
#pragma unroll
      for (int mk = 0; mk < TM; ++mk) {
        float4 av = *(const float4*)(&As[(ty + 16 * mk) * LS + d0]);
#pragma unroll
        for (int nk = 0; nk < TN; ++nk) {
          acc[mk][nk] = fmaf(av.x, b[nk].x, acc[mk][nk]);
          acc[mk][nk] = fmaf(av.y, b[nk].y, acc[mk][nk]);
          acc[mk][nk] = fmaf(av.z, b[nk].z, acc[mk][nk]);
          acc[mk][nk] = fmaf(av.w, b[nk].w, acc[mk][nk]);
        }
      }
    }

    // Update running argmin (j visited in increasing order per thread).
#pragma unroll
    for (int nk = 0; nk < TN; ++nk) {
      const int j = j0 + tx + 16 * nk;
      const float sj = sqt[tx + 16 * nk];
#pragma unroll
      for (int mk = 0; mk < TM; ++mk) {
        const int irow = i0 + ty + 16 * mk;
        float v = fmaf(-2.f, acc[mk][nk], sj);
        if (j != irow && (v < bestv[mk] || (v == bestv[mk] && j < besti[mk]))) {
          bestv[mk] = v;
          besti[mk] = j;
        }
      }
    }
  }

  // Cross-thread reduction: row m is owned by the 16 tx-threads of its ty.
  __syncthreads();
  float* rv = As;        // [BM][16] floats (8 KB, fits in As)
  int* ri = (int*)Bs;    // [BM][16] ints  (8 KB, fits in Bs)
#pragma unroll
  for (int mk = 0; mk < TM; ++mk) {
    int m = ty + 16 * mk;
    rv[m * 16 + tx] = bestv[mk];
    ri[m * 16 + tx] = besti[mk];
  }
  __syncthreads();
  if (tid < BM) {
    float bv = INFINITY;
    int bi = 0x7fffffff;
#pragma unroll
    for (int t = 0; t < 16; ++t) {
      float v = rv[tid * 16 + t];
      int ix = ri[tid * 16 + t];
      if (v < bv || (v == bv && ix < bi)) { bv = v; bi = ix; }
    }
    cand_val[(size_t)(i0 + tid) * JSPLIT + jh] = bv;
    cand_idx[(size_t)(i0 + tid) * JSPLIT + jh] = bi;
  }
}

__global__ void merge_kernel(const float* __restrict__ cand_val,
                             const int* __restrict__ cand_idx,
                             float* __restrict__ out) {
  int i = blockIdx.x * NTHR + threadIdx.x;
  float bv = INFINITY;
  int bi = 0x7fffffff;
#pragma unroll
  for (int s = 0; s < JSPLIT; ++s) {
    float v = cand_val[(size_t)i * JSPLIT + s];
    int ix = cand_idx[(size_t)i * JSPLIT + s];
    if (v < bv || (v == bv && ix < bi)) { bv = v; bi = ix; }
  }
  out[(size_t)i * NPTS + i] = 1.0f;   // self is always nearest (dist ~ 0)
  out[(size_t)i * NPTS + bi] = 1.0f;  // nearest other neighbor
}

extern "C" void kernel_launch(void* const* d_in, const int* in_sizes, int n_in,
                              void* d_out, int out_size, void* d_ws, size_t ws_size,
                              hipStream_t stream) {
  const float* X = (const float*)d_in[0];
  float* out = (float*)d_out;

  // Workspace layout: sq[N] | cand_val[N*JSPLIT] | cand_idx[N*JSPLIT]  (~576 KB)
  float* sq = (float*)d_ws;
  float* cand_val = sq + NPTS;
  int* cand_idx = (int*)(cand_val + (size_t)NPTS * JSPLIT);

  sq_kernel<<<NPTS / NTHR, NTHR, 0, stream>>>(X, sq);
  knn_kernel<<<(NPTS / BM) * JSPLIT, NTHR, 0, stream>>>(X, sq, out, cand_val, cand_idx);
  merge_kernel<<<NPTS / NTHR, NTHR, 0, stream>>>(cand_val, cand_idx, out);
}

// Round 7
// 1221.547 us; speedup vs baseline: 1.2353x; 1.1824x over previous
//
#include <hip/hip_runtime.h>
#include <math.h>

// KNNGraph(2) on N=16384 points, D=64, fp32.
// adjacency = I + one-hot(nearest other neighbor) per row.
// argmin_j (sq[j] - 2*dot(x_i,x_j)), j != i.
//
// R2: fixed scratch spill (25.5ms -> 717us). R3: fused output zeroing.
// R4/R5: LDS-only barriers (stores fire-and-forget). R6: 8x8 fp32 tile (~650us).
// R7: split-bf16 MFMA. dot = hi*hi + lo*hi + hi*lo (err ~1e-4 abs, << NN
//     margins). mfma_f32_16x16x32_bf16, swapped operands: A = j-points (rows),
//     B = i-points (cols) -> D[j,i], C-layout col=lane&15 row=4*(lane>>4)+reg
//     means each lane owns ONE i and a per-lane running argmin. Operand
//     k-mapping uses the consistency trick (same d=8g+e bijection both sides).
//     i-frags resident in 16 VGPRs; j-tiles staged hi|lo in LDS (272 B/row,
//     2-way conflicts only). 35 KB LDS -> 4 blocks/CU, grid 1024 = 4/CU exact.
//     Note: ~690us/iter of timed harness re-poison fill is immovable floor.

#define NPTS 16384
#define DIM 64
#define BI 64           // i-rows per block (4 waves x 16)
#define BJ 128          // j-cols per tile
#define NTHR 256        // 4 waves
#define JSPLIT 4        // j-stripes; grid = 256*4 = 1024 = 4 blocks/CU exact
#define JRANGE (NPTS / JSPLIT)   // 4096
#define NJT (JRANGE / BJ)        // 32 tiles
#define BPITCH 136      // shorts per LDS row: 64 hi + 64 lo + 8 pad (272 B)

typedef __attribute__((ext_vector_type(8))) short s16x8;   // 8 bf16 (4 VGPRs)
typedef __attribute__((ext_vector_type(4))) float f32x4;   // MFMA C/D

// LDS-only barrier: orders ds ops but NOT global stores (zero stream stays
// in flight). Safe: nothing here reads `out`.
#define LDS_BARRIER() asm volatile("s_waitcnt lgkmcnt(0)\n\ts_barrier" ::: "memory")

__device__ __forceinline__ ushort bf16_rn(float x) {
  unsigned u = __float_as_uint(x);
  u += 0x7fffu + ((u >> 16) & 1u);   // round-to-nearest-even
  return (ushort)(u >> 16);
}
__device__ __forceinline__ float bf16_f(ushort h) {
  return __uint_as_float((unsigned)h << 16);
}

__global__ void sq_kernel(const float* __restrict__ X, float* __restrict__ sqout) {
  int i = blockIdx.x * NTHR + threadIdx.x;
  const float4* x4 = (const float4*)(X + (size_t)i * DIM);
  float s = 0.f;
#pragma unroll
  for (int k = 0; k < DIM / 4; ++k) {
    float4 v = x4[k];
    s = fmaf(v.x, v.x, s); s = fmaf(v.y, v.y, s);
    s = fmaf(v.z, v.z, s); s = fmaf(v.w, v.w, s);
  }
  sqout[i] = s;
}

__global__ __launch_bounds__(NTHR, 4) void knn_kernel(
    const float* __restrict__ X, const float* __restrict__ sqn,
    float* __restrict__ out, float* __restrict__ cand_val, int* __restrict__ cand_idx) {
  __shared__ __align__(16) short Bs[BJ * BPITCH];   // 34816 B
  __shared__ float sqt[BJ];                         // 512 B -> 4 blocks/CU

  const int tid = threadIdx.x;
  const int lane = tid & 63;
  const int wid = tid >> 6;       // wave id 0..3 -> i-subtile
  const int li = lane & 15;       // this lane's i within the wave's 16
  const int g = lane >> 4;        // k-slot group / j-quad group
  const int ib = blockIdx.x >> 2; // / JSPLIT
  const int jh = blockIdx.x & 3;  // % JSPLIT
  const int i0 = ib * BI;
  const int j0base = jh * JRANGE;
  const int i_glob = i0 + wid * 16 + li;

  // i-side fragments (MFMA B-operand), resident all kernel: lane holds
  // elements d = 8g+e (A half: d 0..31) and 32+8g+e (B half: d 32..63)
  // of hi(x_i) and lo(x_i). Same (g,e)->d bijection as the j-side reads.
  s16x8 ihiA, iloA, ihiB, iloB;
  {
    const float* xi = X + (size_t)i_glob * DIM;
#pragma unroll
    for (int e = 0; e < 8; ++e) {
      float a = xi[8 * g + e];
      ushort h = bf16_rn(a);
      ihiA[e] = (short)h;
      iloA[e] = (short)bf16_rn(a - bf16_f(h));
      float b = xi[32 + 8 * g + e];
      ushort h2 = bf16_rn(b);
      ihiB[e] = (short)h2;
      iloB[e] = (short)bf16_rn(b - bf16_f(h2));
    }
  }

  float bv = INFINITY;
  int bix = 0x7fffffff;

#pragma unroll 1
  for (int jt = 0; jt < NJT; ++jt) {
    const int j0 = j0base + jt * BJ;
    LDS_BARRIER();   // WAR: previous tile's ds_reads retired
    // Stage j-tile: fp32 -> (hi,lo) bf16 pairs. Row r: shorts [0..63]=hi,
    // [64..127]=lo, 8 pad. 272-B pitch -> 68 dwords -> 2-way conflicts (free).
    {
      const float4* src = (const float4*)(X + (size_t)j0 * DIM);
#pragma unroll
      for (int p = 0; p < (BJ * DIM / 4) / NTHR; ++p) {   // 8
        int f4 = tid + NTHR * p;
        int r = f4 >> 4, c = f4 & 15;
        float4 v = src[f4];
        ushort hx = bf16_rn(v.x), hy = bf16_rn(v.y), hz = bf16_rn(v.z), hw = bf16_rn(v.w);
        ushort lx = bf16_rn(v.x - bf16_f(hx)), ly = bf16_rn(v.y - bf16_f(hy)),
               lz = bf16_rn(v.z - bf16_f(hz)), lw = bf16_rn(v.w - bf16_f(hw));
        uint2 hq = make_uint2((unsigned)hx | ((unsigned)hy << 16),
                              (unsigned)hz | ((unsigned)hw << 16));
        uint2 lq = make_uint2((unsigned)lx | ((unsigned)ly << 16),
                              (unsigned)lz | ((unsigned)lw << 16));
        *(uint2*)(&Bs[r * BPITCH + c * 4]) = hq;
        *(uint2*)(&Bs[r * BPITCH + 64 + c * 4]) = lq;
      }
      if (tid < BJ) sqt[tid] = sqn[j0 + tid];
    }
    LDS_BARRIER();   // Bs/sqt ready; zero stream keeps flowing

    // Zero this block's output stripe (BI x BJ), fire-and-forget.
#pragma unroll
    for (int p = 0; p < (BI * BJ / 4) / NTHR; ++p) {      // 8
      int f4 = tid + NTHR * p;
      int r = f4 >> 5, c = f4 & 31;    // 32 float4 per row
      *(float4*)(out + (size_t)(i0 + r) * NPTS + j0 + c * 4) =
          make_float4(0.f, 0.f, 0.f, 0.f);
    }

    // 8 j-subtiles of 16: per subtile 4 ds_read_b128 + 1 sq read + 6 MFMAs.
    // D[j,i] += hi_j*hi_i (t0,t1) + lo_j*hi_i (t2,t3) + hi_j*lo_i (t4,t5).
#pragma unroll
    for (int s = 0; s < BJ / 16; ++s) {
      const short* jrow = &Bs[(16 * s + li) * BPITCH];
      s16x8 jhiA = *(const s16x8*)(jrow + 8 * g);
      s16x8 jhiB = *(const s16x8*)(jrow + 32 + 8 * g);
      s16x8 jloA = *(const s16x8*)(jrow + 64 + 8 * g);
      s16x8 jloB = *(const s16x8*)(jrow + 96 + 8 * g);
      f32x4 sqv = *(const f32x4*)(&sqt[16 * s + 4 * g]);
      f32x4 acc = {0.f, 0.f, 0.f, 0.f};
      acc = __builtin_amdgcn_mfma_f32_16x16x32_bf16(jhiA, ihiA, acc, 0, 0, 0);
      acc = __builtin_amdgcn_mfma_f32_16x16x32_bf16(jhiB, ihiB, acc, 0, 0, 0);
      acc = __builtin_amdgcn_mfma_f32_16x16x32_bf16(jloA, ihiA, acc, 0, 0, 0);
      acc = __builtin_amdgcn_mfma_f32_16x16x32_bf16(jloB, ihiB, acc, 0, 0, 0);
      acc = __builtin_amdgcn_mfma_f32_16x16x32_bf16(jhiA, iloA, acc, 0, 0, 0);
      acc = __builtin_amdgcn_mfma_f32_16x16x32_bf16(jhiB, iloB, acc, 0, 0, 0);
      // Lane owns i = i_glob; rows r of this lane are j = j0+16s+4g+r.
      // j ascends per lane across (jt,s,r) -> strict < keeps smallest j on tie.
#pragma unroll
      for (int r = 0; r < 4; ++r) {
        float d2 = fmaf(-2.f, acc[r], sqv[r]);
        int j = j0 + 16 * s + 4 * g + r;
        if (j != i_glob && d2 < bv) { bv = d2; bix = j; }
      }
    }
  }

  // Reduce the 4 g-partitions (lanes l, l^16, l^32 hold same i).
  {
    float ov = __shfl_xor(bv, 16, 64);
    int oi = __shfl_xor(bix, 16, 64);
    if (ov < bv || (ov == bv && oi < bix)) { bv = ov; bix = oi; }
    ov = __shfl_xor(bv, 32, 64);
    oi = __shfl_xor(bix, 32, 64);
    if (ov < bv || (ov == bv && oi < bix)) { bv = ov; bix = oi; }
  }
  if (g == 0) {   // lanes 0..15: one writer per i
    cand_val[(size_t)i_glob * JSPLIT + jh] = bv;
    cand_idx[(size_t)i_glob * JSPLIT + jh] = bix;
  }
}

__global__ void merge_kernel(const float* __restrict__ cand_val,
                             const int* __restrict__ cand_idx,
                             float* __restrict__ out) {
  int i = blockIdx.x * NTHR + threadIdx.x;
  float bv = INFINITY;
  int bi = 0x7fffffff;
#pragma unroll
  for (int s = 0; s < JSPLIT; ++s) {
    float v = cand_val[(size_t)i * JSPLIT + s];
    int ix = cand_idx[(size_t)i * JSPLIT + s];
    if (v < bv || (v == bv && ix < bi)) { bv = v; bi = ix; }
  }
  out[(size_t)i * NPTS + i] = 1.0f;   // self is always nearest (dist ~ 0)
  out[(size_t)i * NPTS + bi] = 1.0f;  // nearest other neighbor
}

extern "C" void kernel_launch(void* const* d_in, const int* in_sizes, int n_in,
                              void* d_out, int out_size, void* d_ws, size_t ws_size,
                              hipStream_t stream) {
  const float* X = (const float*)d_in[0];
  float* out = (float*)d_out;

  // Workspace: sq[N] | cand_val[N*JSPLIT] | cand_idx[N*JSPLIT]  (576 KB)
  float* sq = (float*)d_ws;
  float* cand_val = sq + NPTS;
  int* cand_idx = (int*)(cand_val + (size_t)NPTS * JSPLIT);

  sq_kernel<<<NPTS / NTHR, NTHR, 0, stream>>>(X, sq);
  knn_kernel<<<(NPTS / BI) * JSPLIT, NTHR, 0, stream>>>(X, sq, out, cand_val, cand_idx);
  merge_kernel<<<NPTS / NTHR, NTHR, 0, stream>>>(cand_val, cand_idx, out);
}

// Round 8
// 1186.123 us; speedup vs baseline: 1.2722x; 1.0299x over previous
//
#include <hip/hip_runtime.h>
#include <math.h>

// KNNGraph(2) on N=16384 points, D=64, fp32.
// adjacency = I + one-hot(nearest other neighbor) per row.
// argmin_j (sq[j] - 2*dot(x_i,x_j)), j != i.
//
// R2: fixed scratch spill (25.5ms -> 717us). R3: fused output zeroing.
// R4/R5: LDS-only barriers (stores fire-and-forget). R6: 8x8 fp32 tile.
// R7: split-bf16 MFMA (dot = hi*hi + lo*hi + hi*lo), swapped operands so each
//     lane owns ONE i and a per-lane running argmin; knn ~427us, absmax 0.
// R8: zero-store pattern fix. Old: per-tile BIxBJ stripe -> 512-B runs at
//     64-KB stride -> DRAM row thrash, ~2.4 TB/s (the critical path). New:
//     block (ib,jh) zeroes rows [i0,i0+64) x cols [jh*4096,+4096) -- 16-KB
//     contiguous per row, 2 rows per tile iter, same 32 KB/tile/block, still
//     fire-and-forget. Exact partition of `out`; nothing reads it until merge.

#define NPTS 16384
#define DIM 64
#define BI 64           // i-rows per block (4 waves x 16)
#define BJ 128          // j-cols per tile
#define NTHR 256        // 4 waves
#define JSPLIT 4        // j-stripes; grid = 256*4 = 1024 = 4 blocks/CU exact
#define JRANGE (NPTS / JSPLIT)   // 4096
#define NJT (JRANGE / BJ)        // 32 tiles
#define BPITCH 136      // shorts per LDS row: 64 hi + 64 lo + 8 pad (272 B)

typedef __attribute__((ext_vector_type(8))) short s16x8;   // 8 bf16 (4 VGPRs)
typedef __attribute__((ext_vector_type(4))) float f32x4;   // MFMA C/D

// LDS-only barrier: orders ds ops but NOT global stores (zero stream stays
// in flight). Safe: nothing here reads `out`.
#define LDS_BARRIER() asm volatile("s_waitcnt lgkmcnt(0)\n\ts_barrier" ::: "memory")

__device__ __forceinline__ ushort bf16_rn(float x) {
  unsigned u = __float_as_uint(x);
  u += 0x7fffu + ((u >> 16) & 1u);   // round-to-nearest-even
  return (ushort)(u >> 16);
}
__device__ __forceinline__ float bf16_f(ushort h) {
  return __uint_as_float((unsigned)h << 16);
}

__global__ void sq_kernel(const float* __restrict__ X, float* __restrict__ sqout) {
  int i = blockIdx.x * NTHR + threadIdx.x;
  const float4* x4 = (const float4*)(X + (size_t)i * DIM);
  float s = 0.f;
#pragma unroll
  for (int k = 0; k < DIM / 4; ++k) {
    float4 v = x4[k];
    s = fmaf(v.x, v.x, s); s = fmaf(v.y, v.y, s);
    s = fmaf(v.z, v.z, s); s = fmaf(v.w, v.w, s);
  }
  sqout[i] = s;
}

__global__ __launch_bounds__(NTHR, 4) void knn_kernel(
    const float* __restrict__ X, const float* __restrict__ sqn,
    float* __restrict__ out, float* __restrict__ cand_val, int* __restrict__ cand_idx) {
  __shared__ __align__(16) short Bs[BJ * BPITCH];   // 34816 B
  __shared__ float sqt[BJ];                         // 512 B -> 4 blocks/CU

  const int tid = threadIdx.x;
  const int lane = tid & 63;
  const int wid = tid >> 6;       // wave id 0..3 -> i-subtile
  const int li = lane & 15;       // this lane's i within the wave's 16
  const int g = lane >> 4;        // k-slot group / j-quad group
  const int ib = blockIdx.x >> 2; // / JSPLIT
  const int jh = blockIdx.x & 3;  // % JSPLIT
  const int i0 = ib * BI;
  const int j0base = jh * JRANGE;
  const int i_glob = i0 + wid * 16 + li;
  // Zero-region column base for this block (contiguous 4096-col stripe):
  const size_t z0 = (size_t)jh * JRANGE;

  // i-side fragments (MFMA B-operand), resident all kernel: lane holds
  // elements d = 8g+e (A half: d 0..31) and 32+8g+e (B half: d 32..63)
  // of hi(x_i) and lo(x_i). Same (g,e)->d bijection as the j-side reads.
  s16x8 ihiA, iloA, ihiB, iloB;
  {
    const float* xi = X + (size_t)i_glob * DIM;
#pragma unroll
    for (int e = 0; e < 8; ++e) {
      float a = xi[8 * g + e];
      ushort h = bf16_rn(a);
      ihiA[e] = (short)h;
      iloA[e] = (short)bf16_rn(a - bf16_f(h));
      float b = xi[32 + 8 * g + e];
      ushort h2 = bf16_rn(b);
      ihiB[e] = (short)h2;
      iloB[e] = (short)bf16_rn(b - bf16_f(h2));
    }
  }

  float bv = INFINITY;
  int bix = 0x7fffffff;

#pragma unroll 1
  for (int jt = 0; jt < NJT; ++jt) {
    const int j0 = j0base + jt * BJ;
    LDS_BARRIER();   // WAR: previous tile's ds_reads retired
    // Stage j-tile: fp32 -> (hi,lo) bf16 pairs. Row r: shorts [0..63]=hi,
    // [64..127]=lo, 8 pad. 272-B pitch -> 68 dwords -> 2-way conflicts (free).
    {
      const float4* src = (const float4*)(X + (size_t)j0 * DIM);
#pragma unroll
      for (int p = 0; p < (BJ * DIM / 4) / NTHR; ++p) {   // 8
        int f4 = tid + NTHR * p;
        int r = f4 >> 4, c = f4 & 15;
        float4 v = src[f4];
        ushort hx = bf16_rn(v.x), hy = bf16_rn(v.y), hz = bf16_rn(v.z), hw = bf16_rn(v.w);
        ushort lx = bf16_rn(v.x - bf16_f(hx)), ly = bf16_rn(v.y - bf16_f(hy)),
               lz = bf16_rn(v.z - bf16_f(hz)), lw = bf16_rn(v.w - bf16_f(hw));
        uint2 hq = make_uint2((unsigned)hx | ((unsigned)hy << 16),
                              (unsigned)hz | ((unsigned)hw << 16));
        uint2 lq = make_uint2((unsigned)lx | ((unsigned)ly << 16),
                              (unsigned)lz | ((unsigned)lw << 16));
        *(uint2*)(&Bs[r * BPITCH + c * 4]) = hq;
        *(uint2*)(&Bs[r * BPITCH + 64 + c * 4]) = lq;
      }
      if (tid < BJ) sqt[tid] = sqn[j0 + tid];
    }
    LDS_BARRIER();   // Bs/sqt ready; zero stream keeps flowing

    // Zero 2 contiguous 16-KB row-segments of this block's output region:
    // rows i0+2*jt, i0+2*jt+1, cols [jh*4096, +4096). Fire-and-forget:
    // consecutive lanes -> consecutive 16-B chunks, 1 KB/wave-instr.
    {
#pragma unroll
      for (int p = 0; p < 8; ++p) {
        int f4 = tid + NTHR * p;            // 0..2047
        int r = f4 >> 10;                   // 0..1  (1024 float4 per row)
        int c = f4 & 1023;
        *(float4*)(out + (size_t)(i0 + 2 * jt + r) * NPTS + z0 + (size_t)c * 4) =
            make_float4(0.f, 0.f, 0.f, 0.f);
      }
    }

    // 8 j-subtiles of 16: per subtile 4 ds_read_b128 + 1 sq read + 6 MFMAs.
    // D[j,i] += hi_j*hi_i + lo_j*hi_i + hi_j*lo_i.
#pragma unroll
    for (int s = 0; s < BJ / 16; ++s) {
      const short* jrow = &Bs[(16 * s + li) * BPITCH];
      s16x8 jhiA = *(const s16x8*)(jrow + 8 * g);
      s16x8 jhiB = *(const s16x8*)(jrow + 32 + 8 * g);
      s16x8 jloA = *(const s16x8*)(jrow + 64 + 8 * g);
      s16x8 jloB = *(const s16x8*)(jrow + 96 + 8 * g);
      f32x4 sqv = *(const f32x4*)(&sqt[16 * s + 4 * g]);
      f32x4 acc = {0.f, 0.f, 0.f, 0.f};
      acc = __builtin_amdgcn_mfma_f32_16x16x32_bf16(jhiA, ihiA, acc, 0, 0, 0);
      acc = __builtin_amdgcn_mfma_f32_16x16x32_bf16(jhiB, ihiB, acc, 0, 0, 0);
      acc = __builtin_amdgcn_mfma_f32_16x16x32_bf16(jloA, ihiA, acc, 0, 0, 0);
      acc = __builtin_amdgcn_mfma_f32_16x16x32_bf16(jloB, ihiB, acc, 0, 0, 0);
      acc = __builtin_amdgcn_mfma_f32_16x16x32_bf16(jhiA, iloA, acc, 0, 0, 0);
      acc = __builtin_amdgcn_mfma_f32_16x16x32_bf16(jhiB, iloB, acc, 0, 0, 0);
      // Lane owns i = i_glob; rows r of this lane are j = j0+16s+4g+r.
#pragma unroll
      for (int r = 0; r < 4; ++r) {
        float d2 = fmaf(-2.f, acc[r], sqv[r]);
        int j = j0 + 16 * s + 4 * g + r;
        if (j != i_glob && d2 < bv) { bv = d2; bix = j; }
      }
    }
  }

  // Reduce the 4 g-partitions (lanes l, l^16, l^32 hold same i).
  {
    float ov = __shfl_xor(bv, 16, 64);
    int oi = __shfl_xor(bix, 16, 64);
    if (ov < bv || (ov == bv && oi < bix)) { bv = ov; bix = oi; }
    ov = __shfl_xor(bv, 32, 64);
    oi = __shfl_xor(bix, 32, 64);
    if (ov < bv || (ov == bv && oi < bix)) { bv = ov; bix = oi; }
  }
  if (g == 0) {   // lanes 0..15: one writer per i
    cand_val[(size_t)i_glob * JSPLIT + jh] = bv;
    cand_idx[(size_t)i_glob * JSPLIT + jh] = bix;
  }
}

__global__ void merge_kernel(const float* __restrict__ cand_val,
                             const int* __restrict__ cand_idx,
                             float* __restrict__ out) {
  int i = blockIdx.x * NTHR + threadIdx.x;
  float bv = INFINITY;
  int bi = 0x7fffffff;
#pragma unroll
  for (int s = 0; s < JSPLIT; ++s) {
    float v = cand_val[(size_t)i * JSPLIT + s];
    int ix = cand_idx[(size_t)i * JSPLIT + s];
    if (v < bv || (v == bv && ix < bi)) { bv = v; bi = ix; }
  }
  out[(size_t)i * NPTS + i] = 1.0f;   // self is always nearest (dist ~ 0)
  out[(size_t)i * NPTS + bi] = 1.0f;  // nearest other neighbor
}

extern "C" void kernel_launch(void* const* d_in, const int* in_sizes, int n_in,
                              void* d_out, int out_size, void* d_ws, size_t ws_size,
                              hipStream_t stream) {
  const float* X = (const float*)d_in[0];
  float* out = (float*)d_out;

  // Workspace: sq[N] | cand_val[N*JSPLIT] | cand_idx[N*JSPLIT]  (576 KB)
  float* sq = (float*)d_ws;
  float* cand_val = sq + NPTS;
  int* cand_idx = (int*)(cand_val + (size_t)NPTS * JSPLIT);

  sq_kernel<<<NPTS / NTHR, NTHR, 0, stream>>>(X, sq);
  knn_kernel<<<(NPTS / BI) * JSPLIT, NTHR, 0, stream>>>(X, sq, out, cand_val, cand_idx);
  merge_kernel<<<NPTS / NTHR, NTHR, 0, stream>>>(cand_val, cand_idx, out);
}

// Round 9
// 1082.701 us; speedup vs baseline: 1.3937x; 1.0955x over previous
//
#include <hip/hip_runtime.h>
#include <math.h>

// KNNGraph(2) on N=16384 points, D=64, fp32.
// adjacency = I + one-hot(nearest other neighbor) per row.
// argmin_j (sq[j] - 2*dot(x_i,x_j)), j != i.
//
// R7: split-bf16 MFMA (dot = hi*hi + lo*hi + hi*lo), lane-owns-one-i argmin.
// R8: contiguous zero-store rows (+35us). knn ~420us.
// R9: take the bf16 split OFF the critical path. A prep kernel converts X
//     once into Xs[j][128] shorts (64 hi | 64 lo). knn's stage phase becomes
//     a pure 32-KB copy (b128 load + ds_write_b128, no VALU), LDS is linear
//     256 B/row with a 16-B-chunk XOR swizzle (c ^= r&7) -- conflict-free on
//     both write and fragment reads. Zero-stores interleave 1-per-subtile to
//     smooth store-queue pressure. ~690us/iter harness re-poison fill and
//     ~75us fixed overhead are immovable; knn is the only lever.

#define NPTS 16384
#define DIM 64
#define BI 64           // i-rows per block (4 waves x 16)
#define BJ 128          // j-cols per tile
#define NTHR 256        // 4 waves
#define JSPLIT 4        // j-stripes; grid = 256*4 = 1024 = 4 blocks/CU exact
#define JRANGE (NPTS / JSPLIT)   // 4096
#define NJT (JRANGE / BJ)        // 32 tiles
#define RPITCH 128      // shorts per Xs/LDS row: 64 hi + 64 lo (256 B, linear)

typedef __attribute__((ext_vector_type(8))) short s16x8;   // 8 bf16 (4 VGPRs)
typedef __attribute__((ext_vector_type(4))) float f32x4;   // MFMA C/D

// LDS-only barrier: orders ds ops but NOT global stores (zero stream stays
// in flight). Safe: nothing here reads `out`.
#define LDS_BARRIER() asm volatile("s_waitcnt lgkmcnt(0)\n\ts_barrier" ::: "memory")

__device__ __forceinline__ ushort bf16_rn(float x) {
  unsigned u = __float_as_uint(x);
  u += 0x7fffu + ((u >> 16) & 1u);   // round-to-nearest-even
  return (ushort)(u >> 16);
}
__device__ __forceinline__ float bf16_f(ushort h) {
  return __uint_as_float((unsigned)h << 16);
}

// X fp32 [N][64] -> Xs shorts [N][128]: row = 64 hi-bf16 | 64 lo-bf16.
__global__ void split_kernel(const float* __restrict__ X, short* __restrict__ Xs) {
  // 64 rows per block; thread handles float4 chunks (r, c): 4 floats ->
  // 8-B hi pair-write + 8-B lo pair-write. Coalesced within a row.
  const int tid = threadIdx.x;
  const int r0 = blockIdx.x * 64;
#pragma unroll
  for (int p = 0; p < 4; ++p) {
    int f4 = tid + NTHR * p;            // 0..1023
    int r = f4 >> 4, c = f4 & 15;       // row in [0,64), float4 col
    float4 v = ((const float4*)(X + (size_t)(r0 + r) * DIM))[c];
    ushort hx = bf16_rn(v.x), hy = bf16_rn(v.y), hz = bf16_rn(v.z), hw = bf16_rn(v.w);
    ushort lx = bf16_rn(v.x - bf16_f(hx)), ly = bf16_rn(v.y - bf16_f(hy)),
           lz = bf16_rn(v.z - bf16_f(hz)), lw = bf16_rn(v.w - bf16_f(hw));
    short* dst = Xs + (size_t)(r0 + r) * RPITCH;
    *(uint2*)(dst + 4 * c) = make_uint2((unsigned)hx | ((unsigned)hy << 16),
                                        (unsigned)hz | ((unsigned)hw << 16));
    *(uint2*)(dst + 64 + 4 * c) = make_uint2((unsigned)lx | ((unsigned)ly << 16),
                                             (unsigned)lz | ((unsigned)lw << 16));
  }
}

__global__ void sq_kernel(const float* __restrict__ X, float* __restrict__ sqout) {
  int i = blockIdx.x * NTHR + threadIdx.x;
  const float4* x4 = (const float4*)(X + (size_t)i * DIM);
  float s = 0.f;
#pragma unroll
  for (int k = 0; k < DIM / 4; ++k) {
    float4 v = x4[k];
    s = fmaf(v.x, v.x, s); s = fmaf(v.y, v.y, s);
    s = fmaf(v.z, v.z, s); s = fmaf(v.w, v.w, s);
  }
  sqout[i] = s;
}

__global__ __launch_bounds__(NTHR, 4) void knn_kernel(
    const short* __restrict__ Xs, const float* __restrict__ sqn,
    float* __restrict__ out, float* __restrict__ cand_val, int* __restrict__ cand_idx) {
  __shared__ __align__(16) short Bs[BJ * RPITCH];   // 32768 B, linear
  __shared__ float sqt[BJ];                         // 512 B -> 4 blocks/CU

  const int tid = threadIdx.x;
  const int lane = tid & 63;
  const int wid = tid >> 6;       // wave id 0..3 -> i-subtile
  const int li = lane & 15;       // this lane's i within the wave's 16
  const int g = lane >> 4;        // k-slot group / j-quad group
  const int ib = blockIdx.x >> 2; // / JSPLIT
  const int jh = blockIdx.x & 3;  // % JSPLIT
  const int i0 = ib * BI;
  const int j0base = jh * JRANGE;
  const int i_glob = i0 + wid * 16 + li;
  const size_t z0 = (size_t)jh * JRANGE;   // contiguous zero-stripe col base

  // i-side fragments (MFMA B-operand), resident all kernel. Lane holds
  // d = 8g+e of hi/lo for halves A (d 0..31) and B (d 32..63): four aligned
  // 16-B loads from the pre-split Xs row.
  const short* xi = Xs + (size_t)i_glob * RPITCH;
  s16x8 ihiA, ihiB, iloA, iloB;
  {
    uint4 t;
    t = *(const uint4*)(xi + 8 * g);        ihiA = *(s16x8*)&t;
    t = *(const uint4*)(xi + 32 + 8 * g);   ihiB = *(s16x8*)&t;
    t = *(const uint4*)(xi + 64 + 8 * g);   iloA = *(s16x8*)&t;
    t = *(const uint4*)(xi + 96 + 8 * g);   iloB = *(s16x8*)&t;
  }

  float bv = INFINITY;
  int bix = 0x7fffffff;

#pragma unroll 1
  for (int jt = 0; jt < NJT; ++jt) {
    const int j0 = j0base + jt * BJ;
    LDS_BARRIER();   // WAR: previous tile's ds_reads retired
    // Stage j-tile: pure 32-KB copy, no arithmetic. 16-B chunk (r,c) of the
    // global row lands at LDS chunk c^(r&7) of LDS row r (XOR swizzle ->
    // conflict-free fragment reads below; writes also uniform over banks).
    {
      const uint4* src = (const uint4*)(Xs + (size_t)j0 * RPITCH);
#pragma unroll
      for (int p = 0; p < 8; ++p) {
        int ck = tid + NTHR * p;          // 0..2047 chunk index
        int r = ck >> 4, c = ck & 15;
        uint4 v = src[ck];
        *(uint4*)(&Bs[r * RPITCH + ((c ^ (r & 7)) << 3)]) = v;
      }
      if (tid < BJ) sqt[tid] = sqn[j0 + tid];
    }
    LDS_BARRIER();   // Bs/sqt ready; zero stream keeps flowing

    // 8 j-subtiles of 16: 4 swizzled ds_read_b128 + 1 sq read + 6 MFMAs each,
    // plus ONE interleaved zero-store (spreads store-queue pressure).
    // D[j,i] += hi_j*hi_i + lo_j*hi_i + hi_j*lo_i.
#pragma unroll 2
    for (int s = 0; s < BJ / 16; ++s) {
      // Interleaved zero: 16-B chunk #(tid + 256*s) of this tile's 2 rows
      // (rows i0+2*jt .. +1, cols [jh*4096, +4096) -- 16-KB contiguous/row).
      {
        int f4 = tid + NTHR * s;          // 0..2047
        int zr = f4 >> 10, zc = f4 & 1023;
        *(float4*)(out + (size_t)(i0 + 2 * jt + zr) * NPTS + z0 + (size_t)zc * 4) =
            make_float4(0.f, 0.f, 0.f, 0.f);
      }
      const short* jrow = &Bs[(16 * s + li) * RPITCH];
      const int sw = (li & 7);            // row-XOR for this lane's j-row
      s16x8 jhiA = *(const s16x8*)(jrow + (((g) ^ sw) << 3));
      s16x8 jhiB = *(const s16x8*)(jrow + (((4 + g) ^ sw) << 3));
      s16x8 jloA = *(const s16x8*)(jrow + (((8 + g) ^ sw) << 3));
      s16x8 jloB = *(const s16x8*)(jrow + (((12 + g) ^ sw) << 3));
      f32x4 sqv = *(const f32x4*)(&sqt[16 * s + 4 * g]);
      f32x4 acc = {0.f, 0.f, 0.f, 0.f};
      acc = __builtin_amdgcn_mfma_f32_16x16x32_bf16(jhiA, ihiA, acc, 0, 0, 0);
      acc = __builtin_amdgcn_mfma_f32_16x16x32_bf16(jhiB, ihiB, acc, 0, 0, 0);
      acc = __builtin_amdgcn_mfma_f32_16x16x32_bf16(jloA, ihiA, acc, 0, 0, 0);
      acc = __builtin_amdgcn_mfma_f32_16x16x32_bf16(jloB, ihiB, acc, 0, 0, 0);
      acc = __builtin_amdgcn_mfma_f32_16x16x32_bf16(jhiA, iloA, acc, 0, 0, 0);
      acc = __builtin_amdgcn_mfma_f32_16x16x32_bf16(jhiB, iloB, acc, 0, 0, 0);
      // Lane owns i = i_glob; rows r of this lane are j = j0+16s+4g+r
      // (j ascends per lane -> strict < keeps smallest j on ties).
#pragma unroll
      for (int r = 0; r < 4; ++r) {
        float d2 = fmaf(-2.f, acc[r], sqv[r]);
        int j = j0 + 16 * s + 4 * g + r;
        if (j != i_glob && d2 < bv) { bv = d2; bix = j; }
      }
    }
  }

  // Reduce the 4 g-partitions (lanes l, l^16, l^32 hold same i).
  {
    float ov = __shfl_xor(bv, 16, 64);
    int oi = __shfl_xor(bix, 16, 64);
    if (ov < bv || (ov == bv && oi < bix)) { bv = ov; bix = oi; }
    ov = __shfl_xor(bv, 32, 64);
    oi = __shfl_xor(bix, 32, 64);
    if (ov < bv || (ov == bv && oi < bix)) { bv = ov; bix = oi; }
  }
  if (g == 0) {   // lanes 0..15: one writer per i
    cand_val[(size_t)i_glob * JSPLIT + jh] = bv;
    cand_idx[(size_t)i_glob * JSPLIT + jh] = bix;
  }
}

__global__ void merge_kernel(const float* __restrict__ cand_val,
                             const int* __restrict__ cand_idx,
                             float* __restrict__ out) {
  int i = blockIdx.x * NTHR + threadIdx.x;
  float bv = INFINITY;
  int bi = 0x7fffffff;
#pragma unroll
  for (int s = 0; s < JSPLIT; ++s) {
    float v = cand_val[(size_t)i * JSPLIT + s];
    int ix = cand_idx[(size_t)i * JSPLIT + s];
    if (v < bv || (v == bv && ix < bi)) { bv = v; bi = ix; }
  }
  out[(size_t)i * NPTS + i] = 1.0f;   // self is always nearest (dist ~ 0)
  out[(size_t)i * NPTS + bi] = 1.0f;  // nearest other neighbor
}

extern "C" void kernel_launch(void* const* d_in, const int* in_sizes, int n_in,
                              void* d_out, int out_size, void* d_ws, size_t ws_size,
                              hipStream_t stream) {
  const float* X = (const float*)d_in[0];
  float* out = (float*)d_out;

  // Workspace: sq[N] 64KB | cand_val 256KB | cand_idx 256KB | Xs 4MB
  float* sq = (float*)d_ws;
  float* cand_val = sq + NPTS;
  int* cand_idx = (int*)(cand_val + (size_t)NPTS * JSPLIT);
  short* Xs = (short*)(cand_idx + (size_t)NPTS * JSPLIT);

  split_kernel<<<NPTS / 64, NTHR, 0, stream>>>(X, Xs);
  sq_kernel<<<NPTS / NTHR, NTHR, 0, stream>>>(X, sq);
  knn_kernel<<<(NPTS / BI) * JSPLIT, NTHR, 0, stream>>>(Xs, sq, out, cand_val, cand_idx);
  merge_kernel<<<NPTS / NTHR, NTHR, 0, stream>>>(cand_val, cand_idx, out);
}